// Round 8
// baseline (1564.515 us; speedup 1.0000x reference)
//
#include <hip/hip_runtime.h>
#include <math.h>

#define NNODES 50000
#define NEG_SLOPE 0.2f
#define NB 391       // ceil(50000/128) buckets
#define BW 128       // nodes per bucket
#define CHUNK 4096   // edges per block in bin_scatter
#define CAP 8128     // arena slots per bucket in tmp (mean 4224, sigma ~64)

typedef __bf16 bf16x8 __attribute__((ext_vector_type(8)));
typedef float f32x4 __attribute__((ext_vector_type(4)));

// ---------------------------------------------------------------------------
// CSR-lite build: fixed-stride bucket arena; NO per-node CSR (aggregation
// consumes the bucket arena directly).
// ---------------------------------------------------------------------------
__global__ void init_bcur(int* bcur) {
    int i = blockIdx.x * 256 + threadIdx.x;
    if (i < NB) bcur[i] = i * CAP;
}

// Per-block: LDS bucket histogram -> one reservation atomic per bucket ->
// write packed (dst&127)<<16|src into block-private contiguous runs of tmp.
__global__ __launch_bounds__(256) void bin_scatter(const int* __restrict__ ei,
                                                   int E, int N, int* bcur,
                                                   int* __restrict__ tmp) {
    __shared__ int lcnt[NB];
    __shared__ int lbase[NB];
    int tid = threadIdx.x;
    int base0 = blockIdx.x * CHUNK;
    int lim = min(base0 + CHUNK, E + N);
    for (int i = tid; i < NB; i += 256) lcnt[i] = 0;
    __syncthreads();
    for (int e = base0 + tid; e < lim; e += 256) {
        int d = (e < E) ? ei[E + e] : e - E;  // row 1 = dst; tail = self-loops
        atomicAdd(&lcnt[d >> 7], 1);
    }
    __syncthreads();
    for (int b = tid; b < NB; b += 256) {
        int c = lcnt[b];
        lbase[b] = c ? atomicAdd(&bcur[b], c) : 0;
    }
    __syncthreads();
    for (int i = tid; i < NB; i += 256) lcnt[i] = 0;
    __syncthreads();
    for (int e = base0 + tid; e < lim; e += 256) {
        int s, d;
        if (e < E) { s = ei[e]; d = ei[E + e]; }
        else       { s = d = e - E; }
        int b = d >> 7;
        int p = atomicAdd(&lcnt[b], 1);
        tmp[lbase[b] + p] = ((d & 127) << 16) | s;  // src < 50000 < 2^16
    }
}

// ---------------------------------------------------------------------------
// prep_w1: W1[512,64] f32 -> bf16, panelized [k/8][n][k%8] for b-fragments.
// ---------------------------------------------------------------------------
__global__ void prep_w1(const float* __restrict__ W1, __bf16* __restrict__ W1b) {
    int i = blockIdx.x * 256 + threadIdx.x;  // over 512*64
    if (i >= 512 * 64) return;
    int k = i >> 6, n = i & 63;
    W1b[((size_t)(k >> 3) * 64 + n) * 8 + (k & 7)] = (__bf16)W1[i];
}

// ---------------------------------------------------------------------------
// gemm1_mfma + fused att1: H1b[M,64](bf16) = bf16(X) @ bf16(W1); epilogue
// also computes a_src1[n,h], a_dst1[n,h] from the f32 accumulators.
// D-fragment: col = 16t + l15, row = quad*4 + r. h = 2t + (l15>>3);
// att coef for lane = att[16t + l15] (flat [H=8, hid=8] layout).
// ---------------------------------------------------------------------------
__global__ __launch_bounds__(256) void gemm1_mfma(const float* __restrict__ X,
                                                  const __bf16* __restrict__ W1b,
                                                  const float* __restrict__ att_s1,
                                                  const float* __restrict__ att_d1,
                                                  __bf16* __restrict__ H1b,
                                                  float* __restrict__ a_s1,
                                                  float* __restrict__ a_d1,
                                                  int M) {
    __shared__ __bf16 As[2048];  // [kq 0..3][m 0..63][8]
    __shared__ __bf16 Bs[2048];  // [kq 0..3][n 0..63][8]
    int tid = threadIdx.x, wid = tid >> 6, lane = tid & 63;
    int quad = lane >> 4, l15 = lane & 15;
    int m0 = blockIdx.x * 64;
    f32x4 acc[4] = {{0.f, 0.f, 0.f, 0.f}, {0.f, 0.f, 0.f, 0.f},
                    {0.f, 0.f, 0.f, 0.f}, {0.f, 0.f, 0.f, 0.f}};
    int mrow = tid >> 2;   // 0..63 (staging role)
    int kq_w = tid & 3;    // k-chunk (staging role)
    int xrow = min(m0 + mrow, M - 1);  // clamp: garbage rows never stored
    const float* xp = X + (size_t)xrow * 512 + kq_w * 8;
    for (int kb = 0; kb < 16; ++kb) {
        float4 xa = *(const float4*)(xp + kb * 32);
        float4 xb = *(const float4*)(xp + kb * 32 + 4);
        bf16x8 av;
        av[0] = (__bf16)xa.x; av[1] = (__bf16)xa.y;
        av[2] = (__bf16)xa.z; av[3] = (__bf16)xa.w;
        av[4] = (__bf16)xb.x; av[5] = (__bf16)xb.y;
        av[6] = (__bf16)xb.z; av[7] = (__bf16)xb.w;
        *(bf16x8*)(As + ((size_t)kq_w * 64 + mrow) * 8) = av;
        *(bf16x8*)(Bs + ((size_t)wid * 64 + lane) * 8) =
            *(const bf16x8*)(W1b + ((size_t)(kb * 4 + wid) * 64 + lane) * 8);
        __syncthreads();
        bf16x8 af = *(const bf16x8*)(As + ((size_t)quad * 64 + 16 * wid + l15) * 8);
#pragma unroll
        for (int t = 0; t < 4; ++t) {
            bf16x8 bf = *(const bf16x8*)(Bs + ((size_t)quad * 64 + 16 * t + l15) * 8);
            acc[t] = __builtin_amdgcn_mfma_f32_16x16x32_bf16(af, bf, acc[t], 0, 0, 0);
        }
        __syncthreads();
    }
    float asv[4], adv[4];
#pragma unroll
    for (int t = 0; t < 4; ++t) {
        asv[t] = att_s1[16 * t + l15];
        adv[t] = att_d1[16 * t + l15];
    }
#pragma unroll
    for (int t = 0; t < 4; ++t) {
#pragma unroll
        for (int r = 0; r < 4; ++r) {
            int gm = m0 + 16 * wid + quad * 4 + r;
            if (gm < M) H1b[(size_t)gm * 64 + 16 * t + l15] = (__bf16)acc[t][r];
            float ps = acc[t][r] * asv[t];
            float pd = acc[t][r] * adv[t];
            ps += __shfl_xor(ps, 1); ps += __shfl_xor(ps, 2); ps += __shfl_xor(ps, 4);
            pd += __shfl_xor(pd, 1); pd += __shfl_xor(pd, 2); pd += __shfl_xor(pd, 4);
            if (gm < M && (l15 & 7) == 0) {
                int hh = 2 * t + (l15 >> 3);
                a_s1[(size_t)gm * 8 + hh] = ps;
                a_d1[(size_t)gm * 8 + hh] = pd;
            }
        }
    }
}

// ---------------------------------------------------------------------------
// agg1_bucket: one block per bucket (128 dst nodes), 512 thr. Waves stream
// the bucket's edges from tmp (coalesced 64-word chunk + readlane); per edge:
// lane = h*8+c computes w (8 distinct heads) and ds_add_f32 into LDS
// acc[128][64] / den[128][8]. Epilogue: normalize + bias + ReLU -> H1R.
// ---------------------------------------------------------------------------
__global__ __launch_bounds__(512) void agg1_bucket(const int* __restrict__ bcur,
                                                   const int* __restrict__ tmp,
                                                   const __bf16* __restrict__ H1b,
                                                   const float* __restrict__ a_src,
                                                   const float* __restrict__ a_dst,
                                                   const float* __restrict__ b1,
                                                   float* __restrict__ H1R, int N) {
    __shared__ float acc[128 * 64];   // 32KB
    __shared__ float den[128 * 8];    // 4KB
    __shared__ float adst[128 * 8];   // 4KB
    int b = blockIdx.x, tid = threadIdx.x;
    int wave = tid >> 6, lane = tid & 63;
    int base = b * CAP;
    int m = bcur[b] - base;
    for (int i = tid; i < 128 * 64; i += 512) acc[i] = 0.f;
    for (int i = tid; i < 128 * 8; i += 512) {
        den[i] = 0.f;
        int g = b * BW + (i >> 3);
        adst[i] = (g < N) ? a_dst[(size_t)g * 8 + (i & 7)] : 0.f;
    }
    __syncthreads();
    int h = lane >> 3;
    const unsigned short* H1u = (const unsigned short*)H1b;
    for (int i0 = wave * 64; i0 < m; i0 += 512) {
        int j = i0 + lane;
        int word = tmp[base + ((j < m) ? j : (m - 1))];
        int lim = min(64, m - i0);
        for (int q = 0; q < lim; ++q) {  // uniform trip count
            int wq = __builtin_amdgcn_readlane(word, q);
            int k = (wq >> 16) & 127, s = wq & 0xFFFF;
            float e = a_src[(size_t)s * 8 + h] + adst[k * 8 + h];
            e = (e >= 0.f) ? e : NEG_SLOPE * e;
            float w = __expf(e);
            unsigned hv = H1u[(size_t)s * 64 + lane];
            atomicAdd(&acc[k * 64 + lane], w * __uint_as_float(hv << 16));
            if ((lane & 7) == 0) atomicAdd(&den[k * 8 + h], w);
        }
    }
    __syncthreads();
    for (int i = tid; i < 128 * 64; i += 512) {
        int k = i >> 6, c = i & 63;
        int g = b * BW + k;
        if (g < N) {
            float v = acc[i] / (den[k * 8 + (c >> 3)] + 1e-16f) + b1[c];
            H1R[(size_t)g * 64 + c] = (v > 0.f) ? v : 0.f;
        }
    }
}

// ---------------------------------------------------------------------------
// GEMM2 + att2 fused: 16 nodes/block. Wave wid handles 4 nodes sequentially;
// lane = out channel (40 active).
// ---------------------------------------------------------------------------
__global__ __launch_bounds__(256) void gemm2_att2(const float* __restrict__ H1R,
                                                  const float* __restrict__ W2,
                                                  const float* __restrict__ att_src2,
                                                  const float* __restrict__ att_dst2,
                                                  __bf16* __restrict__ H2b,
                                                  float* __restrict__ a_src2,
                                                  float* __restrict__ a_dst2) {
    __shared__ float W2s[64 * 40];
    __shared__ float rows[16][64];
    int tid = threadIdx.x;
    int wid = tid >> 6, lane = tid & 63;
    for (int i = tid; i < 64 * 40; i += 256) W2s[i] = W2[i];
    int nb = blockIdx.x * 16;  // grid exact: 3125*16 = 50000
#pragma unroll
    for (int r = 0; r < 4; ++r)
        rows[r * 4 + wid][lane] = H1R[(size_t)(nb + r * 4 + wid) * 64 + lane];
    __syncthreads();
    int c = lane;
    int cc = (c < 40) ? c : 0;
    float asc = att_src2[cc], adc = att_dst2[cc];
#pragma unroll
    for (int nn = 0; nn < 4; ++nn) {
        int node = nb + wid * 4 + nn;
        const float* rp = rows[wid * 4 + nn];
        float acc = 0.f;
#pragma unroll
        for (int k4 = 0; k4 < 16; ++k4) {
            float4 rv = *(const float4*)(rp + k4 * 4);
            acc += rv.x * W2s[(k4 * 4 + 0) * 40 + cc];
            acc += rv.y * W2s[(k4 * 4 + 1) * 40 + cc];
            acc += rv.z * W2s[(k4 * 4 + 2) * 40 + cc];
            acc += rv.w * W2s[(k4 * 4 + 3) * 40 + cc];
        }
        if (c < 40) H2b[(size_t)node * 40 + c] = (__bf16)acc;
        float ps = (c < 40) ? acc * asc : 0.f;
        float pd = (c < 40) ? acc * adc : 0.f;
#pragma unroll
        for (int mm = 32; mm >= 1; mm >>= 1) {
            ps += __shfl_xor(ps, mm);
            pd += __shfl_xor(pd, mm);
        }
        if (lane == 0) { a_src2[node] = ps; a_dst2[node] = pd; }
    }
}

// ---------------------------------------------------------------------------
// agg2_bucket: one block per bucket, 512 thr. Same streaming pattern; lane =
// channel (40 active) accumulates into LDS acc[128][40]/den[128]; then
// per-node bias + log_softmax straight from LDS -> out.
// ---------------------------------------------------------------------------
__global__ __launch_bounds__(512) void agg2_bucket(const int* __restrict__ bcur,
                                                   const int* __restrict__ tmp,
                                                   const __bf16* __restrict__ H2b,
                                                   const float* __restrict__ a_src2,
                                                   const float* __restrict__ a_d2,
                                                   const float* __restrict__ b2,
                                                   float* __restrict__ out, int N) {
    __shared__ float acc[128 * 40];  // 20KB
    __shared__ float den[128];
    __shared__ float ad[128];
    int b = blockIdx.x, tid = threadIdx.x;
    int wave = tid >> 6, lane = tid & 63;
    int base = b * CAP;
    int m = bcur[b] - base;
    for (int i = tid; i < 128 * 40; i += 512) acc[i] = 0.f;
    if (tid < 128) {
        den[tid] = 0.f;
        int g = b * BW + tid;
        ad[tid] = (g < N) ? a_d2[g] : 0.f;
    }
    __syncthreads();
    const unsigned short* H2u = (const unsigned short*)H2b;
    for (int i0 = wave * 64; i0 < m; i0 += 512) {
        int j = i0 + lane;
        int word = tmp[base + ((j < m) ? j : (m - 1))];
        int lim = min(64, m - i0);
        for (int q = 0; q < lim; ++q) {  // uniform trip count
            int wq = __builtin_amdgcn_readlane(word, q);
            int k = (wq >> 16) & 127, s = wq & 0xFFFF;
            float e = a_src2[s] + ad[k];
            e = (e >= 0.f) ? e : NEG_SLOPE * e;
            float w = __expf(e);
            if (lane < 40) {
                unsigned hv = H2u[(size_t)s * 40 + lane];
                atomicAdd(&acc[k * 40 + lane], w * __uint_as_float(hv << 16));
            }
            if (lane == 0) atomicAdd(&den[k], w);
        }
    }
    __syncthreads();
    int c = lane, cc = (c < 40) ? c : 0;
    float bb = b2[cc];
    for (int k = wave; k < 128; k += 8) {
        int g = b * BW + k;
        if (g >= N) break;  // uniform within wave
        float v = acc[k * 40 + cc] / (den[k] + 1e-16f) + bb;
        float vm = (c < 40) ? v : -3.0e38f;
#pragma unroll
        for (int mm = 32; mm >= 1; mm >>= 1) vm = fmaxf(vm, __shfl_xor(vm, mm));
        float se = (c < 40) ? __expf(v - vm) : 0.f;
#pragma unroll
        for (int mm = 32; mm >= 1; mm >>= 1) se += __shfl_xor(se, mm);
        if (c < 40) out[(size_t)g * 40 + c] = v - vm - __logf(se);
    }
}

// ---------------------------------------------------------------------------
extern "C" void kernel_launch(void* const* d_in, const int* in_sizes, int n_in,
                              void* d_out, int out_size, void* d_ws, size_t ws_size,
                              hipStream_t stream) {
    const float* x   = (const float*)d_in[0];
    const int*   ei  = (const int*)d_in[1];
    const float* W1  = (const float*)d_in[2];
    const float* as1 = (const float*)d_in[3];
    const float* ad1 = (const float*)d_in[4];
    const float* b1  = (const float*)d_in[5];
    const float* W2  = (const float*)d_in[6];
    const float* as2 = (const float*)d_in[7];
    const float* ad2 = (const float*)d_in[8];
    const float* b2  = (const float*)d_in[9];
    float* out = (float*)d_out;

    const int N = NNODES;
    const int E = in_sizes[1] / 2;
    const int total = E + N;

    // workspace carve-up
    char* ws = (char*)d_ws;
    size_t o = 0;
    auto alloc = [&](size_t bytes) -> void* {
        void* p = ws + o;
        o = (o + bytes + 255) & ~(size_t)255;
        return p;
    };
    int* bcur   = (int*)alloc((size_t)NB * 4);
    int* tmp    = (int*)alloc((size_t)NB * CAP * 4);  // 12.7MB bucket arena
    __bf16* W1b = (__bf16*)alloc((size_t)512 * 64 * 2);
    __bf16* H1b = (__bf16*)alloc((size_t)N * 64 * 2);
    float* a_s1 = (float*)alloc((size_t)N * 8 * 4);
    float* a_d1 = (float*)alloc((size_t)N * 8 * 4);
    float* H1R  = (float*)alloc((size_t)N * 64 * 4);
    __bf16* H2b = (__bf16*)alloc((size_t)N * 40 * 2);
    float* a_s2 = (float*)alloc((size_t)N * 4);
    float* a_d2 = (float*)alloc((size_t)N * 4);
    (void)ws_size; (void)n_in; (void)out_size;

    // Bucket-binned edge arena (shared by both layers)
    init_bcur<<<(NB + 255) / 256, 256, 0, stream>>>(bcur);
    bin_scatter<<<(total + CHUNK - 1) / CHUNK, 256, 0, stream>>>(ei, E, N, bcur, tmp);

    // Layer 1
    prep_w1<<<(512 * 64 + 255) / 256, 256, 0, stream>>>(W1, W1b);
    gemm1_mfma<<<(N + 63) / 64, 256, 0, stream>>>(x, W1b, as1, ad1, H1b, a_s1, a_d1, N);
    agg1_bucket<<<NB, 512, 0, stream>>>(bcur, tmp, H1b, a_s1, a_d1, b1, H1R, N);

    // Layer 2
    gemm2_att2<<<N / 16, 256, 0, stream>>>(H1R, W2, as2, ad2, H2b, a_s2, a_d2);
    agg2_bucket<<<NB, 512, 0, stream>>>(bcur, tmp, H2b, a_s2, a_d2, b2, out, N);
}

// Round 9
// 359.478 us; speedup vs baseline: 4.3522x; 4.3522x over previous
//
#include <hip/hip_runtime.h>
#include <math.h>

#define NNODES 50000
#define NEG_SLOPE 0.2f
#define NB 391       // ceil(50000/128) buckets
#define BW 128       // nodes per bucket
#define CHUNK 4096   // edges per block in bin_scatter
#define CAP 8128     // arena slots per bucket in tmp (mean 4224, sigma ~64)

typedef __bf16 bf16x8 __attribute__((ext_vector_type(8)));
typedef float f32x4 __attribute__((ext_vector_type(4)));

// ---------------------------------------------------------------------------
// CSR build: fixed-stride bucket arena for tmp; slot compacted via gcur.
// bcur[NB] doubles as the global compaction cursor (gcur).
// ---------------------------------------------------------------------------
__global__ void init_bcur(int* bcur) {
    int i = blockIdx.x * 256 + threadIdx.x;
    if (i < NB) bcur[i] = i * CAP;
    if (i == NB) bcur[NB] = 0;  // gcur
}

// Per-block: LDS bucket histogram -> one reservation atomic per bucket ->
// write packed (dst&127)<<16|src into block-private contiguous runs of tmp.
__global__ __launch_bounds__(256) void bin_scatter(const int* __restrict__ ei,
                                                   int E, int N, int* bcur,
                                                   int* __restrict__ tmp) {
    __shared__ int lcnt[NB];
    __shared__ int lbase[NB];
    int tid = threadIdx.x;
    int base0 = blockIdx.x * CHUNK;
    int lim = min(base0 + CHUNK, E + N);
    for (int i = tid; i < NB; i += 256) lcnt[i] = 0;
    __syncthreads();
    for (int e = base0 + tid; e < lim; e += 256) {
        int d = (e < E) ? ei[E + e] : e - E;  // row 1 = dst; tail = self-loops
        atomicAdd(&lcnt[d >> 7], 1);
    }
    __syncthreads();
    for (int b = tid; b < NB; b += 256) {
        int c = lcnt[b];
        lbase[b] = c ? atomicAdd(&bcur[b], c) : 0;
    }
    __syncthreads();
    for (int i = tid; i < NB; i += 256) lcnt[i] = 0;
    __syncthreads();
    for (int e = base0 + tid; e < lim; e += 256) {
        int s, d;
        if (e < E) { s = ei[e]; d = ei[E + e]; }
        else       { s = d = e - E; }
        int b = d >> 7;
        int p = atomicAdd(&lcnt[b], 1);
        tmp[lbase[b] + p] = ((d & 127) << 16) | s;  // src < 50000 < 2^16
    }
}

// One block per bucket: per-node LDS count + scan; block reserves m compact
// slots from gcur; writes off/off_end and scatters slot within [cbase,cbase+m).
__global__ __launch_bounds__(256) void csr_finalize(int* __restrict__ bcur,
                                                    const int* __restrict__ tmp,
                                                    int N, int* __restrict__ off,
                                                    int* __restrict__ off_end,
                                                    int* __restrict__ slot) {
    __shared__ int cnt[BW];
    __shared__ int cur[BW];
    __shared__ int cbase_s;
    int b = blockIdx.x, tid = threadIdx.x;
    int base = b * CAP;
    int m = bcur[b] - base;
    if (tid < BW) cnt[tid] = 0;
    __syncthreads();
    for (int i = tid; i < m; i += 256)
        atomicAdd(&cnt[(tmp[base + i] >> 16) & 127], 1);
    __syncthreads();
    if (tid == 0) cbase_s = atomicAdd(&bcur[NB], m);  // compact reservation
    int myv = (tid < BW) ? cnt[tid] : 0;
    for (int o = 1; o < BW; o <<= 1) {
        int u = 0;
        if (tid >= o && tid < BW) u = cnt[tid - o];
        __syncthreads();
        if (tid < BW) cnt[tid] += u;
        __syncthreads();
    }
    if (tid < BW) {
        int ex = cbase_s + cnt[tid] - myv;  // exclusive, compact coords
        cur[tid] = ex;
        int g = b * BW + tid;
        if (g < N) { off[g] = ex; off_end[g] = ex + myv; }
    }
    __syncthreads();
    for (int i = tid; i < m; i += 256) {
        int v = tmp[base + i];
        int k = (v >> 16) & 127;
        int p = atomicAdd(&cur[k], 1);
        slot[p] = v & 0xFFFF;
    }
}

// ---------------------------------------------------------------------------
// prep_w1: W1[512,64] f32 -> bf16, panelized [k/8][n][k%8] for b-fragments.
// ---------------------------------------------------------------------------
__global__ void prep_w1(const float* __restrict__ W1, __bf16* __restrict__ W1b) {
    int i = blockIdx.x * 256 + threadIdx.x;  // over 512*64
    if (i >= 512 * 64) return;
    int k = i >> 6, n = i & 63;
    W1b[((size_t)(k >> 3) * 64 + n) * 8 + (k & 7)] = (__bf16)W1[i];
}

// ---------------------------------------------------------------------------
// gemm1_mfma + fused att1: H1b[M,64](bf16) = bf16(X) @ bf16(W1); epilogue
// also computes a_src1[n,h], a_dst1[n,h] from the f32 accumulators.
// D-fragment: col = 16t + l15, row = quad*4 + r. h = 2t + (l15>>3);
// att coef for lane = att[16t + l15] (flat [H=8, hid=8] layout).
// ---------------------------------------------------------------------------
__global__ __launch_bounds__(256) void gemm1_mfma(const float* __restrict__ X,
                                                  const __bf16* __restrict__ W1b,
                                                  const float* __restrict__ att_s1,
                                                  const float* __restrict__ att_d1,
                                                  __bf16* __restrict__ H1b,
                                                  float* __restrict__ a_s1,
                                                  float* __restrict__ a_d1,
                                                  int M) {
    __shared__ __bf16 As[2048];  // [kq 0..3][m 0..63][8]
    __shared__ __bf16 Bs[2048];  // [kq 0..3][n 0..63][8]
    int tid = threadIdx.x, wid = tid >> 6, lane = tid & 63;
    int quad = lane >> 4, l15 = lane & 15;
    int m0 = blockIdx.x * 64;
    f32x4 acc[4] = {{0.f, 0.f, 0.f, 0.f}, {0.f, 0.f, 0.f, 0.f},
                    {0.f, 0.f, 0.f, 0.f}, {0.f, 0.f, 0.f, 0.f}};
    int mrow = tid >> 2;   // 0..63 (staging role)
    int kq_w = tid & 3;    // k-chunk (staging role)
    int xrow = min(m0 + mrow, M - 1);  // clamp: garbage rows never stored
    const float* xp = X + (size_t)xrow * 512 + kq_w * 8;
    for (int kb = 0; kb < 16; ++kb) {
        float4 xa = *(const float4*)(xp + kb * 32);
        float4 xb = *(const float4*)(xp + kb * 32 + 4);
        bf16x8 av;
        av[0] = (__bf16)xa.x; av[1] = (__bf16)xa.y;
        av[2] = (__bf16)xa.z; av[3] = (__bf16)xa.w;
        av[4] = (__bf16)xb.x; av[5] = (__bf16)xb.y;
        av[6] = (__bf16)xb.z; av[7] = (__bf16)xb.w;
        *(bf16x8*)(As + ((size_t)kq_w * 64 + mrow) * 8) = av;
        *(bf16x8*)(Bs + ((size_t)wid * 64 + lane) * 8) =
            *(const bf16x8*)(W1b + ((size_t)(kb * 4 + wid) * 64 + lane) * 8);
        __syncthreads();
        bf16x8 af = *(const bf16x8*)(As + ((size_t)quad * 64 + 16 * wid + l15) * 8);
#pragma unroll
        for (int t = 0; t < 4; ++t) {
            bf16x8 bf = *(const bf16x8*)(Bs + ((size_t)quad * 64 + 16 * t + l15) * 8);
            acc[t] = __builtin_amdgcn_mfma_f32_16x16x32_bf16(af, bf, acc[t], 0, 0, 0);
        }
        __syncthreads();
    }
    float asv[4], adv[4];
#pragma unroll
    for (int t = 0; t < 4; ++t) {
        asv[t] = att_s1[16 * t + l15];
        adv[t] = att_d1[16 * t + l15];
    }
#pragma unroll
    for (int t = 0; t < 4; ++t) {
#pragma unroll
        for (int r = 0; r < 4; ++r) {
            int gm = m0 + 16 * wid + quad * 4 + r;
            if (gm < M) H1b[(size_t)gm * 64 + 16 * t + l15] = (__bf16)acc[t][r];
            float ps = acc[t][r] * asv[t];
            float pd = acc[t][r] * adv[t];
            ps += __shfl_xor(ps, 1); ps += __shfl_xor(ps, 2); ps += __shfl_xor(ps, 4);
            pd += __shfl_xor(pd, 1); pd += __shfl_xor(pd, 2); pd += __shfl_xor(pd, 4);
            if (gm < M && (l15 & 7) == 0) {
                int hh = 2 * t + (l15 >> 3);
                a_s1[(size_t)gm * 8 + hh] = ps;
                a_d1[(size_t)gm * 8 + hh] = pd;
            }
        }
    }
}

// ---------------------------------------------------------------------------
// agg1: wave per dst node, single pass. s-broadcast via readlane (SGPR base
// for the gather); w-broadcast stays __shfl (lane-dependent source index).
// den accumulated per-lane, reduced once at the end.
// ---------------------------------------------------------------------------
__global__ __launch_bounds__(256) void agg1(const int* __restrict__ off,
                                            const int* __restrict__ off_end,
                                            const int* __restrict__ slot,
                                            const __bf16* __restrict__ H1b,
                                            const float* __restrict__ a_src,
                                            const float* __restrict__ a_dst,
                                            const float* __restrict__ b1,
                                            float* __restrict__ H1R) {
    int wid = threadIdx.x >> 6, lane = threadIdx.x & 63;
    int d = blockIdx.x * 4 + wid;  // grid exact: 12500*4 = 50000
    int beg = off[d], end = off_end[d];
    int h = lane >> 3;   // acc-role head (feature index = lane)
    int eh = lane & 7;   // compute-role head
    int es = lane >> 3;  // compute-role edge sub-index
    float adst_c = a_dst[(size_t)d * 8 + eh];
    float acc = 0.f, den_l = 0.f;
    for (int i = beg; i < end; i += 8) {
        int j = i + es;
        int jj = (j < end) ? j : (end - 1);
        int s = slot[jj];
        float e = a_src[(size_t)s * 8 + eh] + adst_c;
        e = (e >= 0.f) ? e : NEG_SLOPE * e;
        float w = (j < end) ? __expf(e) : 0.f;
        den_l += w;
#pragma unroll
        for (int q = 0; q < 8; ++q) {
            int sq = __builtin_amdgcn_readlane(s, q << 3);
            float wq = __shfl(w, (q << 3) | h);
            acc += wq * (float)H1b[(size_t)sq * 64 + lane];
        }
    }
    // den_l at lane L holds partial for head L&7; reduce over es (bits 3..5)
    den_l += __shfl_xor(den_l, 8);
    den_l += __shfl_xor(den_l, 16);
    den_l += __shfl_xor(den_l, 32);
    float den = __shfl(den_l, h);  // head h lives at lane h (es=0)
    float v = acc / (den + 1e-16f) + b1[lane];
    H1R[(size_t)d * 64 + lane] = (v > 0.f) ? v : 0.f;
}

// ---------------------------------------------------------------------------
// GEMM2 + att2 fused: 16 nodes/block (cuts W2 L2 re-reads 4x). Wave wid
// handles nodes nb+4*wid..+3 sequentially; lane = out channel (40 active).
// ---------------------------------------------------------------------------
__global__ __launch_bounds__(256) void gemm2_att2(const float* __restrict__ H1R,
                                                  const float* __restrict__ W2,
                                                  const float* __restrict__ att_src2,
                                                  const float* __restrict__ att_dst2,
                                                  __bf16* __restrict__ H2b,
                                                  float* __restrict__ a_src2,
                                                  float* __restrict__ a_dst2) {
    __shared__ float W2s[64 * 40];
    __shared__ float rows[16][64];
    int tid = threadIdx.x;
    int wid = tid >> 6, lane = tid & 63;
    for (int i = tid; i < 64 * 40; i += 256) W2s[i] = W2[i];
    int nb = blockIdx.x * 16;  // grid exact: 3125*16 = 50000
#pragma unroll
    for (int r = 0; r < 4; ++r)
        rows[r * 4 + wid][lane] = H1R[(size_t)(nb + r * 4 + wid) * 64 + lane];
    __syncthreads();
    int c = lane;
    int cc = (c < 40) ? c : 0;
    float asc = att_src2[cc], adc = att_dst2[cc];
#pragma unroll
    for (int nn = 0; nn < 4; ++nn) {
        int node = nb + wid * 4 + nn;
        const float* rp = rows[wid * 4 + nn];
        float acc = 0.f;
#pragma unroll
        for (int k4 = 0; k4 < 16; ++k4) {
            float4 rv = *(const float4*)(rp + k4 * 4);
            acc += rv.x * W2s[(k4 * 4 + 0) * 40 + cc];
            acc += rv.y * W2s[(k4 * 4 + 1) * 40 + cc];
            acc += rv.z * W2s[(k4 * 4 + 2) * 40 + cc];
            acc += rv.w * W2s[(k4 * 4 + 3) * 40 + cc];
        }
        if (c < 40) H2b[(size_t)node * 40 + c] = (__bf16)acc;
        float ps = (c < 40) ? acc * asc : 0.f;
        float pd = (c < 40) ? acc * adc : 0.f;
#pragma unroll
        for (int mm = 32; mm >= 1; mm >>= 1) {
            ps += __shfl_xor(ps, mm);
            pd += __shfl_xor(pd, mm);
        }
        if (lane == 0) { a_src2[node] = ps; a_dst2[node] = pd; }
    }
}

// ---------------------------------------------------------------------------
// agg2 + bias + log_softmax: wave per dst node, single pass, bf16 H2 gathers.
// Broadcasts via readlane (SGPR, no LDS pipe); den out of inner loop.
// ---------------------------------------------------------------------------
__global__ __launch_bounds__(256) void agg2(const int* __restrict__ off,
                                            const int* __restrict__ off_end,
                                            const int* __restrict__ slot,
                                            const __bf16* __restrict__ H2b,
                                            const float* __restrict__ a_src2,
                                            const float* __restrict__ a_d2,
                                            const float* __restrict__ b2,
                                            float* __restrict__ out) {
    int wid = threadIdx.x >> 6, lane = threadIdx.x & 63;
    int d = blockIdx.x * 4 + wid;  // grid exact
    int beg = off[d], end = off_end[d];
    float adst = a_d2[d];
    int c = lane;
    int cc = (c < 40) ? c : 0;
    float acc = 0.f, den = 0.f;
    for (int i = beg; i < end; i += 64) {
        int j = i + lane;
        int jj = (j < end) ? j : (end - 1);
        int s = slot[jj];
        float e = a_src2[s] + adst;
        e = (e >= 0.f) ? e : NEG_SLOPE * e;
        float w = (j < end) ? __expf(e) : 0.f;
        den += w;  // per-lane; reduced after the loop
#pragma unroll
        for (int qb = 0; qb < 8; ++qb) {
            if (i + (qb << 3) >= end) break;  // uniform branch
#pragma unroll
            for (int qq = 0; qq < 8; ++qq) {
                int q = (qb << 3) + qq;
                int sq = __builtin_amdgcn_readlane(s, q);
                float wq = __uint_as_float(
                    __builtin_amdgcn_readlane((int)__float_as_uint(w), q));
                acc += wq * (float)H2b[(size_t)sq * 40 + cc];
            }
        }
    }
#pragma unroll
    for (int m = 32; m >= 1; m >>= 1) den += __shfl_xor(den, m);
    float v = acc / (den + 1e-16f) + b2[cc];
    float vm = (c < 40) ? v : -3.0e38f;
#pragma unroll
    for (int m = 32; m >= 1; m >>= 1) vm = fmaxf(vm, __shfl_xor(vm, m));
    float se = (c < 40) ? __expf(v - vm) : 0.f;
#pragma unroll
    for (int m = 32; m >= 1; m >>= 1) se += __shfl_xor(se, m);
    float res = v - vm - __logf(se);
    if (c < 40) out[(size_t)d * 40 + c] = res;
}

// ---------------------------------------------------------------------------
extern "C" void kernel_launch(void* const* d_in, const int* in_sizes, int n_in,
                              void* d_out, int out_size, void* d_ws, size_t ws_size,
                              hipStream_t stream) {
    const float* x   = (const float*)d_in[0];
    const int*   ei  = (const int*)d_in[1];
    const float* W1  = (const float*)d_in[2];
    const float* as1 = (const float*)d_in[3];
    const float* ad1 = (const float*)d_in[4];
    const float* b1  = (const float*)d_in[5];
    const float* W2  = (const float*)d_in[6];
    const float* as2 = (const float*)d_in[7];
    const float* ad2 = (const float*)d_in[8];
    const float* b2  = (const float*)d_in[9];
    float* out = (float*)d_out;

    const int N = NNODES;
    const int E = in_sizes[1] / 2;
    const int total = E + N;

    // workspace carve-up
    char* ws = (char*)d_ws;
    size_t o = 0;
    auto alloc = [&](size_t bytes) -> void* {
        void* p = ws + o;
        o = (o + bytes + 255) & ~(size_t)255;
        return p;
    };
    int* bcur    = (int*)alloc((size_t)(NB + 1) * 4);  // +1: gcur at [NB]
    int* off     = (int*)alloc((size_t)N * 4);
    int* off_end = (int*)alloc((size_t)N * 4);
    int* slot    = (int*)alloc((size_t)total * 4);
    __bf16* W1b = (__bf16*)alloc((size_t)512 * 64 * 2);
    __bf16* H1b = (__bf16*)alloc((size_t)N * 64 * 2);
    float* a_s1 = (float*)alloc((size_t)N * 8 * 4);
    float* a_d1 = (float*)alloc((size_t)N * 8 * 4);
    float* H1R  = (float*)alloc((size_t)N * 64 * 4);
    __bf16* H2b = (__bf16*)alloc((size_t)N * 40 * 2);
    float* a_s2 = (float*)alloc((size_t)N * 4);
    float* a_d2 = (float*)alloc((size_t)N * 4);
    int* tmp = (int*)H1R;  // alias: NB*CAP = 3,178,048 ints <= N*64 floats; dead before agg1
    (void)ws_size; (void)n_in; (void)out_size;

    // CSR build (arena tmp + compacted slot; shared by both layers)
    init_bcur<<<(NB + 256) / 256, 256, 0, stream>>>(bcur);
    bin_scatter<<<(total + CHUNK - 1) / CHUNK, 256, 0, stream>>>(ei, E, N, bcur, tmp);
    csr_finalize<<<NB, 256, 0, stream>>>(bcur, tmp, N, off, off_end, slot);

    // Layer 1 (att1 fused into gemm1 epilogue)
    prep_w1<<<(512 * 64 + 255) / 256, 256, 0, stream>>>(W1, W1b);
    gemm1_mfma<<<(N + 63) / 64, 256, 0, stream>>>(x, W1b, as1, ad1, H1b, a_s1, a_d1, N);
    agg1<<<N / 4, 256, 0, stream>>>(off, off_end, slot, H1b, a_s1, a_d1, b1, H1R);

    // Layer 2
    gemm2_att2<<<N / 16, 256, 0, stream>>>(H1R, W2, as2, ad2, H2b, a_s2, a_d2);
    agg2<<<N / 4, 256, 0, stream>>>(off, off_end, slot, H2b, a_s2, a_d2, b2, out);
}

// Round 10
// 353.110 us; speedup vs baseline: 4.4307x; 1.0180x over previous
//
#include <hip/hip_runtime.h>
#include <math.h>

#define NNODES 50000
#define NEG_SLOPE 0.2f
#define NB 391       // ceil(50000/128) buckets
#define BW 128       // nodes per bucket
#define CHUNK 4096   // edges per block in bin_scatter
#define CAP 8128     // arena slots per bucket in tmp (mean 4224, sigma ~64)

typedef __bf16 bf16x8 __attribute__((ext_vector_type(8)));
typedef float f32x4 __attribute__((ext_vector_type(4)));

// ---------------------------------------------------------------------------
// prep: W1 f32 -> bf16 panels [k/8][n][k%8]  +  bcur arena-cursor init.
// ---------------------------------------------------------------------------
__global__ void prep(const float* __restrict__ W1, __bf16* __restrict__ W1b,
                     int* __restrict__ bcur) {
    int i = blockIdx.x * 256 + threadIdx.x;
    if (i < NB) bcur[i] = i * CAP;
    else if (i == NB) bcur[NB] = 0;  // gcur (slot compaction cursor)
    if (i >= 512 * 64) return;
    int k = i >> 6, n = i & 63;
    W1b[((size_t)(k >> 3) * 64 + n) * 8 + (k & 7)] = (__bf16)W1[i];
}

// ---------------------------------------------------------------------------
// bin_scatter: per-block LDS bucket histogram -> one reservation atomic per
// bucket -> packed (dst&127)<<16|src into block-private contiguous tmp runs.
// ---------------------------------------------------------------------------
__global__ __launch_bounds__(256) void bin_scatter(const int* __restrict__ ei,
                                                   int E, int N, int* bcur,
                                                   int* __restrict__ tmp) {
    __shared__ int lcnt[NB];
    __shared__ int lbase[NB];
    int tid = threadIdx.x;
    int base0 = blockIdx.x * CHUNK;
    int lim = min(base0 + CHUNK, E + N);
    for (int i = tid; i < NB; i += 256) lcnt[i] = 0;
    __syncthreads();
    for (int e = base0 + tid; e < lim; e += 256) {
        int d = (e < E) ? ei[E + e] : e - E;  // row 1 = dst; tail = self-loops
        atomicAdd(&lcnt[d >> 7], 1);
    }
    __syncthreads();
    for (int b = tid; b < NB; b += 256) {
        int c = lcnt[b];
        lbase[b] = c ? atomicAdd(&bcur[b], c) : 0;
    }
    __syncthreads();
    for (int i = tid; i < NB; i += 256) lcnt[i] = 0;
    __syncthreads();
    for (int e = base0 + tid; e < lim; e += 256) {
        int s, d;
        if (e < E) { s = ei[e]; d = ei[E + e]; }
        else       { s = d = e - E; }
        int b = d >> 7;
        int p = atomicAdd(&lcnt[b], 1);
        tmp[lbase[b] + p] = ((d & 127) << 16) | s;  // src < 50000 < 2^16
    }
}

// ---------------------------------------------------------------------------
// csr_finalize: one block per bucket; per-node LDS count + scan; block
// reserves m compact slots from gcur; writes off/off_end and scatters slot.
// ---------------------------------------------------------------------------
__global__ __launch_bounds__(256) void csr_finalize(int* __restrict__ bcur,
                                                    const int* __restrict__ tmp,
                                                    int N, int* __restrict__ off,
                                                    int* __restrict__ off_end,
                                                    int* __restrict__ slot) {
    __shared__ int cnt[BW];
    __shared__ int cur[BW];
    __shared__ int cbase_s;
    int b = blockIdx.x, tid = threadIdx.x;
    int base = b * CAP;
    int m = bcur[b] - base;
    if (tid < BW) cnt[tid] = 0;
    __syncthreads();
    for (int i = tid; i < m; i += 256)
        atomicAdd(&cnt[(tmp[base + i] >> 16) & 127], 1);
    __syncthreads();
    if (tid == 0) cbase_s = atomicAdd(&bcur[NB], m);  // compact reservation
    int myv = (tid < BW) ? cnt[tid] : 0;
    for (int o = 1; o < BW; o <<= 1) {
        int u = 0;
        if (tid >= o && tid < BW) u = cnt[tid - o];
        __syncthreads();
        if (tid < BW) cnt[tid] += u;
        __syncthreads();
    }
    if (tid < BW) {
        int ex = cbase_s + cnt[tid] - myv;  // exclusive, compact coords
        cur[tid] = ex;
        int g = b * BW + tid;
        if (g < N) { off[g] = ex; off_end[g] = ex + myv; }
    }
    __syncthreads();
    for (int i = tid; i < m; i += 256) {
        int v = tmp[base + i];
        int k = (v >> 16) & 127;
        int p = atomicAdd(&cur[k], 1);
        slot[p] = v & 0xFFFF;
    }
}

// ---------------------------------------------------------------------------
// gemm1_mfma + fused att1: H1b[M,64](bf16) = bf16(X) @ bf16(W1); epilogue
// also computes a_src1[n,h], a_dst1[n,h] from the f32 accumulators.
// D-fragment: col = 16t + l15, row = quad*4 + r. h = 2t + (l15>>3).
// ---------------------------------------------------------------------------
__global__ __launch_bounds__(256) void gemm1_mfma(const float* __restrict__ X,
                                                  const __bf16* __restrict__ W1b,
                                                  const float* __restrict__ att_s1,
                                                  const float* __restrict__ att_d1,
                                                  __bf16* __restrict__ H1b,
                                                  float* __restrict__ a_s1,
                                                  float* __restrict__ a_d1,
                                                  int M) {
    __shared__ __bf16 As[2048];  // [kq 0..3][m 0..63][8]
    __shared__ __bf16 Bs[2048];  // [kq 0..3][n 0..63][8]
    int tid = threadIdx.x, wid = tid >> 6, lane = tid & 63;
    int quad = lane >> 4, l15 = lane & 15;
    int m0 = blockIdx.x * 64;
    f32x4 acc[4] = {{0.f, 0.f, 0.f, 0.f}, {0.f, 0.f, 0.f, 0.f},
                    {0.f, 0.f, 0.f, 0.f}, {0.f, 0.f, 0.f, 0.f}};
    int mrow = tid >> 2;   // 0..63 (staging role)
    int kq_w = tid & 3;    // k-chunk (staging role)
    int xrow = min(m0 + mrow, M - 1);  // clamp: garbage rows never stored
    const float* xp = X + (size_t)xrow * 512 + kq_w * 8;
    for (int kb = 0; kb < 16; ++kb) {
        float4 xa = *(const float4*)(xp + kb * 32);
        float4 xb = *(const float4*)(xp + kb * 32 + 4);
        bf16x8 av;
        av[0] = (__bf16)xa.x; av[1] = (__bf16)xa.y;
        av[2] = (__bf16)xa.z; av[3] = (__bf16)xa.w;
        av[4] = (__bf16)xb.x; av[5] = (__bf16)xb.y;
        av[6] = (__bf16)xb.z; av[7] = (__bf16)xb.w;
        *(bf16x8*)(As + ((size_t)kq_w * 64 + mrow) * 8) = av;
        *(bf16x8*)(Bs + ((size_t)wid * 64 + lane) * 8) =
            *(const bf16x8*)(W1b + ((size_t)(kb * 4 + wid) * 64 + lane) * 8);
        __syncthreads();
        bf16x8 af = *(const bf16x8*)(As + ((size_t)quad * 64 + 16 * wid + l15) * 8);
#pragma unroll
        for (int t = 0; t < 4; ++t) {
            bf16x8 bf = *(const bf16x8*)(Bs + ((size_t)quad * 64 + 16 * t + l15) * 8);
            acc[t] = __builtin_amdgcn_mfma_f32_16x16x32_bf16(af, bf, acc[t], 0, 0, 0);
        }
        __syncthreads();
    }
    float asv[4], adv[4];
#pragma unroll
    for (int t = 0; t < 4; ++t) {
        asv[t] = att_s1[16 * t + l15];
        adv[t] = att_d1[16 * t + l15];
    }
#pragma unroll
    for (int t = 0; t < 4; ++t) {
#pragma unroll
        for (int r = 0; r < 4; ++r) {
            int gm = m0 + 16 * wid + quad * 4 + r;
            if (gm < M) H1b[(size_t)gm * 64 + 16 * t + l15] = (__bf16)acc[t][r];
            float ps = acc[t][r] * asv[t];
            float pd = acc[t][r] * adv[t];
            ps += __shfl_xor(ps, 1); ps += __shfl_xor(ps, 2); ps += __shfl_xor(ps, 4);
            pd += __shfl_xor(pd, 1); pd += __shfl_xor(pd, 2); pd += __shfl_xor(pd, 4);
            if (gm < M && (l15 & 7) == 0) {
                int hh = 2 * t + (l15 >> 3);
                a_s1[(size_t)gm * 8 + hh] = ps;
                a_d1[(size_t)gm * 8 + hh] = pd;
            }
        }
    }
}

// ---------------------------------------------------------------------------
// agg1_fused: wave per dst node (proven R6 inner loop), epilogue now runs the
// layer-2 GEMM + att2 directly from the wave's relu'd row (W2 in LDS) — the
// H1R intermediate and the separate gemm2_att2 kernel are deleted.
// ---------------------------------------------------------------------------
__global__ __launch_bounds__(256) void agg1_fused(const int* __restrict__ off,
                                                  const int* __restrict__ off_end,
                                                  const int* __restrict__ slot,
                                                  const __bf16* __restrict__ H1b,
                                                  const float* __restrict__ a_src,
                                                  const float* __restrict__ a_dst,
                                                  const float* __restrict__ b1,
                                                  const float* __restrict__ W2,
                                                  const float* __restrict__ att_src2,
                                                  const float* __restrict__ att_dst2,
                                                  __bf16* __restrict__ H2b,
                                                  float* __restrict__ a_s2,
                                                  float* __restrict__ a_d2) {
    __shared__ float W2s[64 * 40];  // 10KB
    __shared__ float rows[4][64];
    int tid = threadIdx.x;
    int wid = tid >> 6, lane = tid & 63;
    for (int i = tid; i < 64 * 40; i += 256) W2s[i] = W2[i];
    __syncthreads();  // W2s visible before any wave reaches the epilogue
    int d = blockIdx.x * 4 + wid;  // grid exact: 12500*4 = 50000
    int beg = off[d], end = off_end[d];
    int h = lane >> 3;   // acc-role head (feature index = lane)
    int eh = lane & 7;   // compute-role head
    int es = lane >> 3;  // compute-role edge sub-index
    float adst_c = a_dst[(size_t)d * 8 + eh];
    float acc = 0.f, den_l = 0.f;
    for (int i = beg; i < end; i += 8) {
        int j = i + es;
        int jj = (j < end) ? j : (end - 1);
        int s = slot[jj];
        float e = a_src[(size_t)s * 8 + eh] + adst_c;
        e = (e >= 0.f) ? e : NEG_SLOPE * e;
        float w = (j < end) ? __expf(e) : 0.f;
        den_l += w;
#pragma unroll
        for (int q = 0; q < 8; ++q) {
            int sq = __builtin_amdgcn_readlane(s, q << 3);
            float wq = __shfl(w, (q << 3) | h);
            acc += wq * (float)H1b[(size_t)sq * 64 + lane];
        }
    }
    den_l += __shfl_xor(den_l, 8);
    den_l += __shfl_xor(den_l, 16);
    den_l += __shfl_xor(den_l, 32);
    float den = __shfl(den_l, h);
    float v = acc / (den + 1e-16f) + b1[lane];
    v = (v > 0.f) ? v : 0.f;   // = H1R row of node d, lane = channel
    // ---- fused layer-2 GEMM + att2 (per-wave, no barrier needed) ----
    rows[wid][lane] = v;
    int c = lane, cc = (c < 40) ? c : 0;
    float acc2 = 0.f;
    const float* rp = rows[wid];
#pragma unroll 8
    for (int k = 0; k < 64; ++k) acc2 += rp[k] * W2s[k * 40 + cc];
    if (c < 40) H2b[(size_t)d * 40 + c] = (__bf16)acc2;
    float ps = (c < 40) ? acc2 * att_src2[cc] : 0.f;
    float pd = (c < 40) ? acc2 * att_dst2[cc] : 0.f;
#pragma unroll
    for (int mm = 32; mm >= 1; mm >>= 1) {
        ps += __shfl_xor(ps, mm);
        pd += __shfl_xor(pd, mm);
    }
    if (lane == 0) { a_s2[d] = ps; a_d2[d] = pd; }
}

// ---------------------------------------------------------------------------
// agg2 + bias + log_softmax: wave per dst node, single pass, bf16 H2 gathers.
// Broadcasts via readlane (SGPR, no LDS pipe); den out of inner loop.
// ---------------------------------------------------------------------------
__global__ __launch_bounds__(256) void agg2(const int* __restrict__ off,
                                            const int* __restrict__ off_end,
                                            const int* __restrict__ slot,
                                            const __bf16* __restrict__ H2b,
                                            const float* __restrict__ a_src2,
                                            const float* __restrict__ a_d2,
                                            const float* __restrict__ b2,
                                            float* __restrict__ out) {
    int wid = threadIdx.x >> 6, lane = threadIdx.x & 63;
    int d = blockIdx.x * 4 + wid;  // grid exact
    int beg = off[d], end = off_end[d];
    float adst = a_d2[d];
    int c = lane;
    int cc = (c < 40) ? c : 0;
    float acc = 0.f, den = 0.f;
    for (int i = beg; i < end; i += 64) {
        int j = i + lane;
        int jj = (j < end) ? j : (end - 1);
        int s = slot[jj];
        float e = a_src2[s] + adst;
        e = (e >= 0.f) ? e : NEG_SLOPE * e;
        float w = (j < end) ? __expf(e) : 0.f;
        den += w;  // per-lane; reduced after the loop
#pragma unroll
        for (int qb = 0; qb < 8; ++qb) {
            if (i + (qb << 3) >= end) break;  // uniform branch
#pragma unroll
            for (int qq = 0; qq < 8; ++qq) {
                int q = (qb << 3) + qq;
                int sq = __builtin_amdgcn_readlane(s, q);
                float wq = __uint_as_float(
                    __builtin_amdgcn_readlane((int)__float_as_uint(w), q));
                acc += wq * (float)H2b[(size_t)sq * 40 + cc];
            }
        }
    }
#pragma unroll
    for (int m = 32; m >= 1; m >>= 1) den += __shfl_xor(den, m);
    float v = acc / (den + 1e-16f) + b2[cc];
    float vm = (c < 40) ? v : -3.0e38f;
#pragma unroll
    for (int m = 32; m >= 1; m >>= 1) vm = fmaxf(vm, __shfl_xor(vm, m));
    float se = (c < 40) ? __expf(v - vm) : 0.f;
#pragma unroll
    for (int m = 32; m >= 1; m >>= 1) se += __shfl_xor(se, m);
    float res = v - vm - __logf(se);
    if (c < 40) out[(size_t)d * 40 + c] = res;
}

// ---------------------------------------------------------------------------
extern "C" void kernel_launch(void* const* d_in, const int* in_sizes, int n_in,
                              void* d_out, int out_size, void* d_ws, size_t ws_size,
                              hipStream_t stream) {
    const float* x   = (const float*)d_in[0];
    const int*   ei  = (const int*)d_in[1];
    const float* W1  = (const float*)d_in[2];
    const float* as1 = (const float*)d_in[3];
    const float* ad1 = (const float*)d_in[4];
    const float* b1  = (const float*)d_in[5];
    const float* W2  = (const float*)d_in[6];
    const float* as2 = (const float*)d_in[7];
    const float* ad2 = (const float*)d_in[8];
    const float* b2  = (const float*)d_in[9];
    float* out = (float*)d_out;

    const int N = NNODES;
    const int E = in_sizes[1] / 2;
    const int total = E + N;

    // workspace carve-up
    char* ws = (char*)d_ws;
    size_t o = 0;
    auto alloc = [&](size_t bytes) -> void* {
        void* p = ws + o;
        o = (o + bytes + 255) & ~(size_t)255;
        return p;
    };
    int* bcur    = (int*)alloc((size_t)(NB + 1) * 4);  // +1: gcur at [NB]
    int* off     = (int*)alloc((size_t)N * 4);
    int* off_end = (int*)alloc((size_t)N * 4);
    int* slot    = (int*)alloc((size_t)total * 4);
    int* tmp     = (int*)alloc((size_t)NB * CAP * 4);  // 12.7MB bucket arena
    __bf16* W1b = (__bf16*)alloc((size_t)512 * 64 * 2);
    __bf16* H1b = (__bf16*)alloc((size_t)N * 64 * 2);
    float* a_s1 = (float*)alloc((size_t)N * 8 * 4);
    float* a_d1 = (float*)alloc((size_t)N * 8 * 4);
    __bf16* H2b = (__bf16*)alloc((size_t)N * 40 * 2);
    float* a_s2 = (float*)alloc((size_t)N * 4);
    float* a_d2 = (float*)alloc((size_t)N * 4);
    (void)ws_size; (void)n_in; (void)out_size;

    // prep (W1 pack + bcur init), then binned CSR build (shared by layers)
    prep<<<(512 * 64 + 255) / 256, 256, 0, stream>>>(W1, W1b, bcur);
    bin_scatter<<<(total + CHUNK - 1) / CHUNK, 256, 0, stream>>>(ei, E, N, bcur, tmp);
    csr_finalize<<<NB, 256, 0, stream>>>(bcur, tmp, N, off, off_end, slot);

    // Layer 1 GEMM (+att1 fused)
    gemm1_mfma<<<(N + 63) / 64, 256, 0, stream>>>(x, W1b, as1, ad1, H1b, a_s1, a_d1, N);

    // Layer-1 aggregation + fused layer-2 GEMM/att2
    agg1_fused<<<N / 4, 256, 0, stream>>>(off, off_end, slot, H1b, a_s1, a_d1, b1,
                                          W2, as2, ad2, H2b, a_s2, a_d2);

    // Layer-2 aggregation + bias + log_softmax
    agg2<<<N / 4, 256, 0, stream>>>(off, off_end, slot, H2b, a_s2, a_d2, b2, out);
}